// Round 4
// baseline (916.721 us; speedup 1.0000x reference)
//
#include <hip/hip_runtime.h>
#include <hip/hip_bf16.h>
#include <math.h>

#define DCH 256
#define HWD 128

typedef __attribute__((ext_vector_type(4))) float f32x4;
typedef __attribute__((ext_vector_type(8))) short s16x8;
typedef __attribute__((ext_vector_type(4))) short s16x4;

__device__ __forceinline__ float b2f(unsigned short u) {
    union { float f; unsigned int i; } c; c.i = ((unsigned int)u) << 16; return c.f;
}
__device__ __forceinline__ unsigned short f2b(float f) {
    union { float f; unsigned int i; } c; c.f = f;
    unsigned int r = c.i + 0x7FFFu + ((c.i >> 16) & 1u);
    return (unsigned short)(r >> 16);
}
// tanh-form gelu via native v_exp_f32
__device__ __forceinline__ float gelu_f(float z) {
    float y = z * (1.0f + 0.044715f * z * z);
    float p = exp2f(-2.3022108f * y);
    return z / (1.0f + p);
}

// ---------------- weight prep: fp32 -> bf16, W1/W2 transposed ----------------
__global__ void prep_weights(const float* __restrict__ W1, const float* __restrict__ W2,
                             const float* __restrict__ Wsf, const float* __restrict__ Wsh,
                             const float* __restrict__ Wsq,
                             unsigned short* __restrict__ w1t, unsigned short* __restrict__ w2t,
                             unsigned short* __restrict__ wsf, unsigned short* __restrict__ wsh,
                             unsigned short* __restrict__ wsq)
{
    int idx = blockIdx.x * 256 + threadIdx.x;
    if (idx < 3 * 512 * 256) {               // w1t[g][n][k] = W1[g][k][n]
        int g = idx / (512 * 256); int r = idx % (512 * 256);
        int n = r / 256, k = r % 256;
        w1t[idx] = f2b(W1[((size_t)g * 256 + k) * 512 + n]);
    }
    if (idx < 3 * 256 * 256) {               // w2t[g][n][k] = W2[g][k][n]
        int g = idx / (256 * 256); int r = idx % (256 * 256);
        int n = r / 256, k = r % 256;
        w2t[idx] = f2b(W2[((size_t)g * 256 + k) * 256 + n]);
    }
    if (idx < 64 * 64) wsf[idx] = f2b(Wsf[idx]);
    if (idx < 32 * 32) wsh[idx] = f2b(Wsh[idx]);
    if (idx < 16 * 16) wsq[idx] = f2b(Wsq[idx]);
}

// ---------------- fused per-segment gMLP: 1024 threads (16 waves), 2 blocks/CU ----------------
// LDS: region A = Y[LSEG][DP] -> stats4 -> P ; region B = stats1 -> Vt[256][VTP] -> O(bf16)
// U and residual x live in registers.
template<int LSEG, int GROUP>
__global__ __launch_bounds__(1024, 8)
void gmlp_kernel(const float* __restrict__ x,
                 const float* __restrict__ ln1_g, const float* __restrict__ ln1_b,
                 const float* __restrict__ b1,
                 const float* __restrict__ sgu_g, const float* __restrict__ sgu_b,
                 const float* __restrict__ bs, const float* __restrict__ b2,
                 const unsigned short* __restrict__ w1t,
                 const unsigned short* __restrict__ w2t,
                 const unsigned short* __restrict__ wsp,
                 float* __restrict__ out)
{
    constexpr int TPT = 1024 / LSEG;          // threads per token
    constexpr int CPT = DCH / TPT;            // channels per thread
    constexpr int DP  = 264;                  // bf16 row stride
    constexpr int M16 = LSEG / 16;
    constexpr int VTP = LSEG + 8;             // Vt row stride (tokens)
    constexpr int SZY  = LSEG * DP * 2;
    constexpr int SZVT = 256 * VTP * 2;
    static_assert(SZVT >= SZY, "O(bf16) must fit over Vt");
    static_assert(SZVT >= 2 * 1024 * 4 && SZY >= 2 * 1024 * 4, "stats fit");

    __shared__ __align__(16) unsigned char smem[SZY + SZVT];
    unsigned short* sm_y  = (unsigned short*)smem;            // Y, later P
    unsigned short* sm_vt = (unsigned short*)(smem + SZY);    // Vt, later O (stride DP)
    float* part1 = (float*)(smem + SZY);                      // stats ph1-2 (Vt dead)
    float* part4 = (float*)smem;                              // stats ph4 (Y dead)

    const int bid = blockIdx.x;               // natural order (no swizzle — R3 showed regression)

    int b, hr0, wr0, pr, pc;
    const int t = threadIdx.x & (LSEG - 1);
    if constexpr (LSEG == 64) {
        b = bid / 225; int rem = bid % 225;
        hr0 = (rem / 15) * 8; wr0 = (rem % 15) * 8;
        pr = t >> 3; pc = t & 7;
    } else if constexpr (LSEG == 32) {
        int ix = bid;
        if (ix < 480) {                       // l / r vertical strips (8 rows x 4 cols)
            int side = ix / 240; int j = ix % 240;
            b = j / 15; hr0 = (j % 15) * 8; wr0 = 120 + 4 * side;
            pr = t >> 2; pc = t & 3;
        } else {                              // u / d horizontal strips (4 rows x 8 cols)
            ix -= 480; int side = ix / 240; int j = ix % 240;
            b = j / 15; hr0 = 120 + 4 * side; wr0 = (j % 15) * 8;
            pr = t >> 3; pc = t & 7;
        }
    } else {                                  // quadrants 4x4
        int quad = bid >> 4; b = bid & 15;
        hr0 = 120 + 4 * (quad >> 1); wr0 = 120 + 4 * (quad & 1);
        pr = t >> 2; pc = t & 3;
    }

    const int tid  = threadIdx.x;
    const int lane = tid & 63;
    const int wv   = tid >> 6;                // 0..15
    const int l16  = lane & 15;
    const int l4   = lane >> 4;
    const int dq   = tid / LSEG;
    const int d0   = dq * CPT;

    const int hq = (hr0 + pr + 4) & (HWD - 1);
    const int wq = (wr0 + pc + 4) & (HWD - 1);
    const size_t plane = (size_t)HWD * HWD;
    const size_t pix = (size_t)hq * HWD + wq;
    const float* xp = x + (size_t)b * DCH * plane + pix;

    // ---- Phase 1: gather x + per-token partial stats; residual packed in regs ----
    unsigned int xres[CPT / 2];
    {
        float s1 = 0.f, s2 = 0.f;
        #pragma unroll
        for (int i = 0; i < CPT; i += 2) {
            float v0 = xp[(size_t)(d0 + i) * plane];
            float v1 = xp[(size_t)(d0 + i + 1) * plane];
            s1 += v0 + v1; s2 += v0 * v0 + v1 * v1;
            xres[i / 2] = (unsigned int)f2b(v0) | ((unsigned int)f2b(v1) << 16);
        }
        part1[(0 * TPT + dq) * LSEG + t] = s1;
        part1[(1 * TPT + dq) * LSEG + t] = s2;
    }
    __syncthreads();

    // ---- Phase 2: LN1 -> Y ----
    {
        float mu = 0.f, sq = 0.f;
        #pragma unroll
        for (int q = 0; q < TPT; ++q) {
            mu += part1[(0 * TPT + q) * LSEG + t];
            sq += part1[(1 * TPT + q) * LSEG + t];
        }
        mu *= (1.0f / DCH);
        float var = sq * (1.0f / DCH) - mu * mu;
        float rs = rsqrtf(var + 1e-5f);
        #pragma unroll
        for (int i = 0; i < CPT; i += 4) {
            f32x4 g  = *(const f32x4*)&ln1_g[GROUP * DCH + d0 + i];
            f32x4 bv = *(const f32x4*)&ln1_b[GROUP * DCH + d0 + i];
            s16x4 yv;
            #pragma unroll
            for (int j = 0; j < 4; ++j) {
                unsigned int pk = xres[(i + j) / 2];
                float v = b2f((unsigned short)((j & 1) ? (pk >> 16) : (pk & 0xFFFF)));
                yv[j] = (short)f2b((v - mu) * rs * g[j] + bv[j]);
            }
            *(s16x4*)&sm_y[t * DP + d0 + i] = yv;
        }
    }
    __syncthreads();

    // ---- Phase 3: GEMM1. Wave owns 16 cols of U (regs) and 16 cols of V (-> Vt transposed) ----
    unsigned int u_pk[M16][2];                // gelu(U) packed bf16, [mi][r-pair]
    {
        // U pass
        f32x4 acc[M16];
        #pragma unroll
        for (int mi = 0; mi < M16; ++mi) acc[mi] = f32x4{0.f, 0.f, 0.f, 0.f};
        const unsigned short* wpu = w1t + (size_t)GROUP * 512 * 256 + (size_t)(wv * 16) * 256;
        #pragma unroll
        for (int k0 = 0; k0 < 256; k0 += 32) {
            s16x8 a[M16];
            #pragma unroll
            for (int mi = 0; mi < M16; ++mi)
                a[mi] = *(const s16x8*)&sm_y[(16 * mi + l16) * DP + k0 + 8 * l4];
            s16x8 bb = *(const s16x8*)&wpu[(size_t)l16 * 256 + k0 + 8 * l4];
            #pragma unroll
            for (int mi = 0; mi < M16; ++mi)
                acc[mi] = __builtin_amdgcn_mfma_f32_16x16x32_bf16(a[mi], bb, acc[mi], 0, 0, 0);
        }
        {
            float b1v = b1[GROUP * 512 + wv * 16 + l16];
            #pragma unroll
            for (int mi = 0; mi < M16; ++mi) {
                float z0 = gelu_f(acc[mi][0] + b1v);
                float z1 = gelu_f(acc[mi][1] + b1v);
                float z2 = gelu_f(acc[mi][2] + b1v);
                float z3 = gelu_f(acc[mi][3] + b1v);
                u_pk[mi][0] = (unsigned int)f2b(z0) | ((unsigned int)f2b(z1) << 16);
                u_pk[mi][1] = (unsigned int)f2b(z2) | ((unsigned int)f2b(z3) << 16);
            }
        }
        // V pass
        #pragma unroll
        for (int mi = 0; mi < M16; ++mi) acc[mi] = f32x4{0.f, 0.f, 0.f, 0.f};
        const unsigned short* wpv = w1t + (size_t)GROUP * 512 * 256 + (size_t)(256 + wv * 16) * 256;
        #pragma unroll
        for (int k0 = 0; k0 < 256; k0 += 32) {
            s16x8 a[M16];
            #pragma unroll
            for (int mi = 0; mi < M16; ++mi)
                a[mi] = *(const s16x8*)&sm_y[(16 * mi + l16) * DP + k0 + 8 * l4];
            s16x8 bb = *(const s16x8*)&wpv[(size_t)l16 * 256 + k0 + 8 * l4];
            #pragma unroll
            for (int mi = 0; mi < M16; ++mi)
                acc[mi] = __builtin_amdgcn_mfma_f32_16x16x32_bf16(a[mi], bb, acc[mi], 0, 0, 0);
        }
        {
            int row = wv * 16 + l16;                          // V channel -> Vt row
            float b1v = b1[GROUP * 512 + 256 + wv * 16 + l16];
            #pragma unroll
            for (int mi = 0; mi < M16; ++mi) {
                s16x4 vp;
                #pragma unroll
                for (int r = 0; r < 4; ++r)
                    vp[r] = (short)f2b(gelu_f(acc[mi][r] + b1v));
                *(s16x4*)&sm_vt[row * VTP + 16 * mi + 4 * l4] = vp;
            }
        }
    }
    __syncthreads();

    // ---- Phase 4: LN (sgu) over Vt columns, in place ----
    {
        float s1 = 0.f, s2 = 0.f;
        #pragma unroll
        for (int i = 0; i < CPT; ++i) {
            float f = b2f(sm_vt[(d0 + i) * VTP + t]);
            s1 += f; s2 += f * f;
        }
        part4[(0 * TPT + dq) * LSEG + t] = s1;
        part4[(1 * TPT + dq) * LSEG + t] = s2;
    }
    __syncthreads();
    {
        float mu = 0.f, sq = 0.f;
        #pragma unroll
        for (int q = 0; q < TPT; ++q) {
            mu += part4[(0 * TPT + q) * LSEG + t];
            sq += part4[(1 * TPT + q) * LSEG + t];
        }
        mu *= (1.0f / DCH);
        float var = sq * (1.0f / DCH) - mu * mu;
        float rs = rsqrtf(var + 1e-5f);
        #pragma unroll
        for (int i = 0; i < CPT; i += 4) {
            f32x4 g  = *(const f32x4*)&sgu_g[GROUP * DCH + d0 + i];
            f32x4 bv = *(const f32x4*)&sgu_b[GROUP * DCH + d0 + i];
            #pragma unroll
            for (int j = 0; j < 4; ++j) {
                int d = d0 + i + j;
                float f = b2f(sm_vt[d * VTP + t]);
                sm_vt[d * VTP + t] = f2b((f - mu) * rs * g[j] + bv[j]);
            }
        }
    }
    __syncthreads();

    // ---- Phase 5: token-mix  Vm = Ws @ V + bs ; P = u .* Vm -> Y region ----
    {
        f32x4 acc[M16];
        #pragma unroll
        for (int mi = 0; mi < M16; ++mi) acc[mi] = f32x4{0.f, 0.f, 0.f, 0.f};
        const int row = wv * 16 + l16;        // V channel (output col)
        constexpr int KS = (LSEG >= 32) ? (LSEG / 32) : 1;
        #pragma unroll
        for (int ks = 0; ks < KS; ++ks) {
            const int k0 = 32 * ks;
            const s16x8 z8 = {0,0,0,0,0,0,0,0};
            s16x8 a[M16], bv;
            #pragma unroll
            for (int mi = 0; mi < M16; ++mi) {
                if constexpr (LSEG == 16)
                    a[mi] = (l4 < 2) ? *(const s16x8*)&wsp[(16 * mi + l16) * LSEG + 8 * l4] : z8;
                else
                    a[mi] = *(const s16x8*)&wsp[(16 * mi + l16) * LSEG + k0 + 8 * l4];
            }
            if constexpr (LSEG == 16)
                bv = (l4 < 2) ? *(const s16x8*)&sm_vt[row * VTP + 8 * l4] : z8;
            else
                bv = *(const s16x8*)&sm_vt[row * VTP + k0 + 8 * l4];
            #pragma unroll
            for (int mi = 0; mi < M16; ++mi)
                acc[mi] = __builtin_amdgcn_mfma_f32_16x16x32_bf16(a[mi], bv, acc[mi], 0, 0, 0);
        }
        #pragma unroll
        for (int mi = 0; mi < M16; ++mi) {
            #pragma unroll
            for (int r = 0; r < 4; ++r) {
                int m = 16 * mi + 4 * l4 + r;
                unsigned int pk = u_pk[mi][r >> 1];
                float uf = b2f((unsigned short)((r & 1) ? (pk >> 16) : (pk & 0xFFFF)));
                float p = (acc[mi][r] + bs[m]) * uf;
                sm_y[m * DP + wv * 16 + l16] = f2b(p);
            }
        }
    }
    __syncthreads();

    // ---- Phase 6: GEMM2  O = P @ W2 + b2 -> bf16 over Vt region (stride DP) ----
    {
        f32x4 acc[M16];
        #pragma unroll
        for (int mi = 0; mi < M16; ++mi) acc[mi] = f32x4{0.f, 0.f, 0.f, 0.f};
        const unsigned short* wp2 = w2t + (size_t)GROUP * 256 * 256 + (size_t)(wv * 16) * 256;
        #pragma unroll
        for (int k0 = 0; k0 < 256; k0 += 32) {
            s16x8 a[M16];
            #pragma unroll
            for (int mi = 0; mi < M16; ++mi)
                a[mi] = *(const s16x8*)&sm_y[(16 * mi + l16) * DP + k0 + 8 * l4];
            s16x8 bb = *(const s16x8*)&wp2[(size_t)l16 * 256 + k0 + 8 * l4];
            #pragma unroll
            for (int mi = 0; mi < M16; ++mi)
                acc[mi] = __builtin_amdgcn_mfma_f32_16x16x32_bf16(a[mi], bb, acc[mi], 0, 0, 0);
        }
        const int cu = wv * 16 + l16;
        float b2v = b2[GROUP * DCH + cu];
        #pragma unroll
        for (int mi = 0; mi < M16; ++mi) {
            #pragma unroll
            for (int r = 0; r < 4; ++r) {
                int m = 16 * mi + 4 * l4 + r;
                sm_vt[m * DP + cu] = f2b(acc[mi][r] + b2v);
            }
        }
    }
    __syncthreads();

    // ---- Phase 7: residual add (regs) + scatter ----
    {
        float* op = out + (size_t)b * DCH * plane + pix;
        #pragma unroll
        for (int i = 0; i < CPT; i += 4) {
            s16x4 ov = *(s16x4*)&sm_vt[t * DP + d0 + i];
            #pragma unroll
            for (int j = 0; j < 4; ++j) {
                unsigned int pk = xres[(i + j) / 2];
                float xr = b2f((unsigned short)(((i + j) & 1) ? (pk >> 16) : (pk & 0xFFFF)));
                op[(size_t)(d0 + i + j) * plane] = b2f((unsigned short)ov[j]) + xr;
            }
        }
    }
}

extern "C" void kernel_launch(void* const* d_in, const int* in_sizes, int n_in,
                              void* d_out, int out_size, void* d_ws, size_t ws_size,
                              hipStream_t stream)
{
    (void)in_sizes; (void)n_in; (void)out_size; (void)ws_size;
    const float* x     = (const float*)d_in[0];
    const float* ln1_g = (const float*)d_in[1];
    const float* ln1_b = (const float*)d_in[2];
    const float* W1    = (const float*)d_in[3];
    const float* b1    = (const float*)d_in[4];
    const float* sgu_g = (const float*)d_in[5];
    const float* sgu_b = (const float*)d_in[6];
    const float* Wsf   = (const float*)d_in[7];
    const float* bsf   = (const float*)d_in[8];
    const float* Wsh   = (const float*)d_in[9];
    const float* bsh   = (const float*)d_in[10];
    const float* Wsq   = (const float*)d_in[11];
    const float* bsq   = (const float*)d_in[12];
    const float* W2    = (const float*)d_in[13];
    const float* b2    = (const float*)d_in[14];
    float* out = (float*)d_out;

    unsigned short* w1t = (unsigned short*)d_ws;       // 3*512*256 bf16
    unsigned short* w2t = w1t + 3 * 512 * 256;         // 3*256*256 bf16
    unsigned short* wsf = w2t + 3 * 256 * 256;         // 64*64
    unsigned short* wsh = wsf + 64 * 64;               // 32*32
    unsigned short* wsq = wsh + 32 * 32;               // 16*16

    hipLaunchKernelGGL(prep_weights, dim3(1536), dim3(256), 0, stream,
                       W1, W2, Wsf, Wsh, Wsq, w1t, w2t, wsf, wsh, wsq);

    hipLaunchKernelGGL((gmlp_kernel<64, 0>), dim3(3600), dim3(1024), 0, stream,
                       x, ln1_g, ln1_b, b1, sgu_g, sgu_b, bsf, b2, w1t, w2t, wsf, out);
    hipLaunchKernelGGL((gmlp_kernel<32, 1>), dim3(960), dim3(1024), 0, stream,
                       x, ln1_g, ln1_b, b1, sgu_g, sgu_b, bsh, b2, w1t, w2t, wsh, out);
    hipLaunchKernelGGL((gmlp_kernel<16, 2>), dim3(64), dim3(1024), 0, stream,
                       x, ln1_g, ln1_b, b1, sgu_g, sgu_b, bsq, b2, w1t, w2t, wsq, out);
}

// Round 5
// 616.143 us; speedup vs baseline: 1.4878x; 1.4878x over previous
//
#include <hip/hip_runtime.h>
#include <hip/hip_bf16.h>
#include <math.h>

#define DCH 256
#define HWD 128

typedef __attribute__((ext_vector_type(4))) float f32x4;
typedef __attribute__((ext_vector_type(8))) short s16x8;
typedef __attribute__((ext_vector_type(4))) short s16x4;

__device__ __forceinline__ float b2f(unsigned short u) {
    union { float f; unsigned int i; } c; c.i = ((unsigned int)u) << 16; return c.f;
}
// native cvt (compiler emits v_cvt_pk_bf16_f32 for pairs)
__device__ __forceinline__ unsigned short f2b(float f) {
    union { __hip_bfloat16 h; unsigned short u; } c; c.h = __float2bfloat16(f); return c.u;
}
__device__ __forceinline__ unsigned int f2b2(float lo, float hi) {
    return (unsigned int)f2b(lo) | ((unsigned int)f2b(hi) << 16);
}
// tanh-form gelu via native v_exp_f32
__device__ __forceinline__ float gelu_f(float z) {
    float y = z * (1.0f + 0.044715f * z * z);
    float p = exp2f(-2.3022108f * y);
    return z / (1.0f + p);
}

// ---------------- weight prep: fp32 -> bf16, W1/W2 transposed ----------------
__global__ void prep_weights(const float* __restrict__ W1, const float* __restrict__ W2,
                             const float* __restrict__ Wsf, const float* __restrict__ Wsh,
                             const float* __restrict__ Wsq,
                             unsigned short* __restrict__ w1t, unsigned short* __restrict__ w2t,
                             unsigned short* __restrict__ wsf, unsigned short* __restrict__ wsh,
                             unsigned short* __restrict__ wsq)
{
    int idx = blockIdx.x * 256 + threadIdx.x;
    if (idx < 3 * 512 * 256) {               // w1t[g][n][k] = W1[g][k][n]
        int g = idx / (512 * 256); int r = idx % (512 * 256);
        int n = r / 256, k = r % 256;
        w1t[idx] = f2b(W1[((size_t)g * 256 + k) * 512 + n]);
    }
    if (idx < 3 * 256 * 256) {               // w2t[g][n][k] = W2[g][k][n]
        int g = idx / (256 * 256); int r = idx % (256 * 256);
        int n = r / 256, k = r % 256;
        w2t[idx] = f2b(W2[((size_t)g * 256 + k) * 256 + n]);
    }
    if (idx < 64 * 64) wsf[idx] = f2b(Wsf[idx]);
    if (idx < 32 * 32) wsh[idx] = f2b(Wsh[idx]);
    if (idx < 16 * 16) wsq[idx] = f2b(Wsq[idx]);
}

// ---------------- fused per-segment gMLP body: 512 threads (8 waves) ----------------
// LDS: region A = Y[LSEG][DP] -> stats4 -> P ; region B = stats1 -> Vt[256][VTP] -> O(bf16)
// U and residual x live in registers.
template<int LSEG, int GROUP>
__device__ __forceinline__
void gmlp_body(int b, int hr0, int wr0, int pr, int pc,
               const float* __restrict__ x,
               const float* __restrict__ ln1_g, const float* __restrict__ ln1_b,
               const float* __restrict__ b1,
               const float* __restrict__ sgu_g, const float* __restrict__ sgu_b,
               const float* __restrict__ bs, const float* __restrict__ b2,
               const unsigned short* __restrict__ w1t,
               const unsigned short* __restrict__ w2t,
               const unsigned short* __restrict__ wsp,
               float* __restrict__ out,
               unsigned char* smem)
{
    constexpr int TPT = 512 / LSEG;           // threads per token
    constexpr int CPT = DCH / TPT;            // channels per thread
    constexpr int DP  = 264;                  // bf16 row stride
    constexpr int M16 = LSEG / 16;
    constexpr int VTP = LSEG + 8;             // Vt row stride (tokens)
    constexpr int SZY  = LSEG * DP * 2;
    constexpr int SZVT = 256 * VTP * 2;
    static_assert(SZY + SZVT <= 70656, "LDS budget");
    static_assert(SZVT >= SZY, "O(bf16) must fit over Vt");

    unsigned short* sm_y  = (unsigned short*)smem;            // Y, later P
    unsigned short* sm_vt = (unsigned short*)(smem + SZY);    // Vt, later O (stride DP)
    float* part1 = (float*)(smem + SZY);                      // stats ph1-2 (Vt dead)
    float* part4 = (float*)smem;                              // stats ph4 (Y dead)

    const int tid  = threadIdx.x;
    const int lane = tid & 63;
    const int wv   = tid >> 6;                // 0..7
    const int l16  = lane & 15;
    const int l4   = lane >> 4;
    const int t    = tid & (LSEG - 1);
    const int dq   = tid / LSEG;
    const int d0   = dq * CPT;

    const int hq = (hr0 + pr + 4) & (HWD - 1);
    const int wq = (wr0 + pc + 4) & (HWD - 1);
    const size_t plane = (size_t)HWD * HWD;
    const size_t pix = (size_t)hq * HWD + wq;
    const float* xp = x + (size_t)b * DCH * plane + pix;

    // ---- Phase 1: gather x + per-token partial stats; residual packed in regs ----
    unsigned int xres[CPT / 2];
    {
        float s1 = 0.f, s2 = 0.f;
        #pragma unroll
        for (int i = 0; i < CPT; i += 2) {
            float v0 = xp[(size_t)(d0 + i) * plane];
            float v1 = xp[(size_t)(d0 + i + 1) * plane];
            s1 += v0 + v1; s2 += v0 * v0 + v1 * v1;
            xres[i / 2] = f2b2(v0, v1);
        }
        part1[(0 * TPT + dq) * LSEG + t] = s1;
        part1[(1 * TPT + dq) * LSEG + t] = s2;
    }
    __syncthreads();

    // ---- Phase 2: LN1 -> Y ----
    {
        float mu = 0.f, sq = 0.f;
        #pragma unroll
        for (int q = 0; q < TPT; ++q) {
            mu += part1[(0 * TPT + q) * LSEG + t];
            sq += part1[(1 * TPT + q) * LSEG + t];
        }
        mu *= (1.0f / DCH);
        float var = sq * (1.0f / DCH) - mu * mu;
        float rs = rsqrtf(var + 1e-5f);
        #pragma unroll
        for (int i = 0; i < CPT; i += 4) {
            f32x4 g  = *(const f32x4*)&ln1_g[GROUP * DCH + d0 + i];
            f32x4 bv = *(const f32x4*)&ln1_b[GROUP * DCH + d0 + i];
            float z[4];
            #pragma unroll
            for (int j = 0; j < 4; ++j) {
                unsigned int pk = xres[(i + j) / 2];
                float v = b2f((unsigned short)((j & 1) ? (pk >> 16) : (pk & 0xFFFF)));
                z[j] = (v - mu) * rs * g[j] + bv[j];
            }
            s16x4 yv;
            yv[0] = (short)f2b(z[0]); yv[1] = (short)f2b(z[1]);
            yv[2] = (short)f2b(z[2]); yv[3] = (short)f2b(z[3]);
            *(s16x4*)&sm_y[t * DP + d0 + i] = yv;
        }
    }
    __syncthreads();

    // ---- Phase 3: GEMM1. Wave owns 32 cols of U (regs) and 32 cols of V (-> Vt transposed) ----
    unsigned int u_pk[M16][2][2];             // gelu(U) packed bf16, [mi][ni][r-pair]
    {
        // U pass
        f32x4 acc[M16][2];
        #pragma unroll
        for (int mi = 0; mi < M16; ++mi) { acc[mi][0] = f32x4{0,0,0,0}; acc[mi][1] = f32x4{0,0,0,0}; }
        const unsigned short* wpu = w1t + (size_t)GROUP * 512 * 256 + (size_t)(wv * 32) * 256;
        __builtin_amdgcn_s_setprio(1);
        #pragma unroll
        for (int k0 = 0; k0 < 256; k0 += 32) {
            s16x8 a[M16], bb[2];
            #pragma unroll
            for (int mi = 0; mi < M16; ++mi)
                a[mi] = *(const s16x8*)&sm_y[(16 * mi + l16) * DP + k0 + 8 * l4];
            #pragma unroll
            for (int ni = 0; ni < 2; ++ni)
                bb[ni] = *(const s16x8*)&wpu[(size_t)(16 * ni + l16) * 256 + k0 + 8 * l4];
            #pragma unroll
            for (int mi = 0; mi < M16; ++mi)
                #pragma unroll
                for (int ni = 0; ni < 2; ++ni)
                    acc[mi][ni] = __builtin_amdgcn_mfma_f32_16x16x32_bf16(a[mi], bb[ni], acc[mi][ni], 0, 0, 0);
        }
        __builtin_amdgcn_s_setprio(0);
        #pragma unroll
        for (int ni = 0; ni < 2; ++ni) {
            float b1v = b1[GROUP * 512 + wv * 32 + 16 * ni + l16];
            #pragma unroll
            for (int mi = 0; mi < M16; ++mi) {
                float z0 = gelu_f(acc[mi][ni][0] + b1v);
                float z1 = gelu_f(acc[mi][ni][1] + b1v);
                float z2 = gelu_f(acc[mi][ni][2] + b1v);
                float z3 = gelu_f(acc[mi][ni][3] + b1v);
                u_pk[mi][ni][0] = f2b2(z0, z1);
                u_pk[mi][ni][1] = f2b2(z2, z3);
            }
        }
        // V pass
        #pragma unroll
        for (int mi = 0; mi < M16; ++mi) { acc[mi][0] = f32x4{0,0,0,0}; acc[mi][1] = f32x4{0,0,0,0}; }
        const unsigned short* wpv = w1t + (size_t)GROUP * 512 * 256 + (size_t)(256 + wv * 32) * 256;
        __builtin_amdgcn_s_setprio(1);
        #pragma unroll
        for (int k0 = 0; k0 < 256; k0 += 32) {
            s16x8 a[M16], bb[2];
            #pragma unroll
            for (int mi = 0; mi < M16; ++mi)
                a[mi] = *(const s16x8*)&sm_y[(16 * mi + l16) * DP + k0 + 8 * l4];
            #pragma unroll
            for (int ni = 0; ni < 2; ++ni)
                bb[ni] = *(const s16x8*)&wpv[(size_t)(16 * ni + l16) * 256 + k0 + 8 * l4];
            #pragma unroll
            for (int mi = 0; mi < M16; ++mi)
                #pragma unroll
                for (int ni = 0; ni < 2; ++ni)
                    acc[mi][ni] = __builtin_amdgcn_mfma_f32_16x16x32_bf16(a[mi], bb[ni], acc[mi][ni], 0, 0, 0);
        }
        __builtin_amdgcn_s_setprio(0);
        #pragma unroll
        for (int ni = 0; ni < 2; ++ni) {
            int row = wv * 32 + 16 * ni + l16;              // V channel -> Vt row
            float b1v = b1[GROUP * 512 + 256 + wv * 32 + 16 * ni + l16];
            #pragma unroll
            for (int mi = 0; mi < M16; ++mi) {
                s16x4 vp;
                #pragma unroll
                for (int r = 0; r < 4; ++r)
                    vp[r] = (short)f2b(gelu_f(acc[mi][ni][r] + b1v));
                *(s16x4*)&sm_vt[row * VTP + 16 * mi + 4 * l4] = vp;
            }
        }
    }
    __syncthreads();

    // ---- Phase 4: LN (sgu) over Vt columns, in place ----
    {
        float s1 = 0.f, s2 = 0.f;
        #pragma unroll
        for (int i = 0; i < CPT; ++i) {
            float f = b2f(sm_vt[(d0 + i) * VTP + t]);
            s1 += f; s2 += f * f;
        }
        part4[(0 * TPT + dq) * LSEG + t] = s1;
        part4[(1 * TPT + dq) * LSEG + t] = s2;
    }
    __syncthreads();
    {
        float mu = 0.f, sq = 0.f;
        #pragma unroll
        for (int q = 0; q < TPT; ++q) {
            mu += part4[(0 * TPT + q) * LSEG + t];
            sq += part4[(1 * TPT + q) * LSEG + t];
        }
        mu *= (1.0f / DCH);
        float var = sq * (1.0f / DCH) - mu * mu;
        float rs = rsqrtf(var + 1e-5f);
        #pragma unroll
        for (int i = 0; i < CPT; i += 4) {
            f32x4 g  = *(const f32x4*)&sgu_g[GROUP * DCH + d0 + i];
            f32x4 bv = *(const f32x4*)&sgu_b[GROUP * DCH + d0 + i];
            #pragma unroll
            for (int j = 0; j < 4; ++j) {
                int d = d0 + i + j;
                float f = b2f(sm_vt[d * VTP + t]);
                sm_vt[d * VTP + t] = f2b((f - mu) * rs * g[j] + bv[j]);
            }
        }
    }
    __syncthreads();

    // ---- Phase 5: token-mix  Vm = Ws @ V + bs ; P = u .* Vm -> Y region ----
    {
        f32x4 acc[M16][2];
        #pragma unroll
        for (int mi = 0; mi < M16; ++mi) { acc[mi][0] = f32x4{0,0,0,0}; acc[mi][1] = f32x4{0,0,0,0}; }
        constexpr int KS = (LSEG >= 32) ? (LSEG / 32) : 1;
        __builtin_amdgcn_s_setprio(1);
        #pragma unroll
        for (int ks = 0; ks < KS; ++ks) {
            const int k0 = 32 * ks;
            const s16x8 z8 = {0,0,0,0,0,0,0,0};
            s16x8 a[M16], bb[2];
            #pragma unroll
            for (int mi = 0; mi < M16; ++mi) {
                if constexpr (LSEG == 16)
                    a[mi] = (l4 < 2) ? *(const s16x8*)&wsp[(16 * mi + l16) * LSEG + 8 * l4] : z8;
                else
                    a[mi] = *(const s16x8*)&wsp[(16 * mi + l16) * LSEG + k0 + 8 * l4];
            }
            #pragma unroll
            for (int ni = 0; ni < 2; ++ni) {
                int row = wv * 32 + 16 * ni + l16;
                if constexpr (LSEG == 16)
                    bb[ni] = (l4 < 2) ? *(const s16x8*)&sm_vt[row * VTP + 8 * l4] : z8;
                else
                    bb[ni] = *(const s16x8*)&sm_vt[row * VTP + k0 + 8 * l4];
            }
            #pragma unroll
            for (int mi = 0; mi < M16; ++mi)
                #pragma unroll
                for (int ni = 0; ni < 2; ++ni)
                    acc[mi][ni] = __builtin_amdgcn_mfma_f32_16x16x32_bf16(a[mi], bb[ni], acc[mi][ni], 0, 0, 0);
        }
        __builtin_amdgcn_s_setprio(0);
        #pragma unroll
        for (int mi = 0; mi < M16; ++mi) {
            #pragma unroll
            for (int r = 0; r < 4; ++r) {
                int m = 16 * mi + 4 * l4 + r;
                float bsm = bs[m];
                #pragma unroll
                for (int ni = 0; ni < 2; ++ni) {
                    unsigned int pk = u_pk[mi][ni][r >> 1];
                    float uf = b2f((unsigned short)((r & 1) ? (pk >> 16) : (pk & 0xFFFF)));
                    float p = (acc[mi][ni][r] + bsm) * uf;
                    sm_y[m * DP + wv * 32 + 16 * ni + l16] = f2b(p);
                }
            }
        }
    }
    __syncthreads();

    // ---- Phase 6: GEMM2  O = P @ W2 + b2 -> bf16 over Vt region (stride DP) ----
    {
        f32x4 acc[M16][2];
        #pragma unroll
        for (int mi = 0; mi < M16; ++mi) { acc[mi][0] = f32x4{0,0,0,0}; acc[mi][1] = f32x4{0,0,0,0}; }
        const int nb2 = wv * 32;
        const unsigned short* wp2 = w2t + (size_t)GROUP * 256 * 256 + (size_t)nb2 * 256;
        __builtin_amdgcn_s_setprio(1);
        #pragma unroll
        for (int k0 = 0; k0 < 256; k0 += 32) {
            s16x8 a[M16], bb[2];
            #pragma unroll
            for (int mi = 0; mi < M16; ++mi)
                a[mi] = *(const s16x8*)&sm_y[(16 * mi + l16) * DP + k0 + 8 * l4];
            #pragma unroll
            for (int ni = 0; ni < 2; ++ni)
                bb[ni] = *(const s16x8*)&wp2[(size_t)(16 * ni + l16) * 256 + k0 + 8 * l4];
            #pragma unroll
            for (int mi = 0; mi < M16; ++mi)
                #pragma unroll
                for (int ni = 0; ni < 2; ++ni)
                    acc[mi][ni] = __builtin_amdgcn_mfma_f32_16x16x32_bf16(a[mi], bb[ni], acc[mi][ni], 0, 0, 0);
        }
        __builtin_amdgcn_s_setprio(0);
        #pragma unroll
        for (int ni = 0; ni < 2; ++ni) {
            int cu = nb2 + 16 * ni + l16;
            float b2v = b2[GROUP * DCH + cu];
            #pragma unroll
            for (int mi = 0; mi < M16; ++mi) {
                #pragma unroll
                for (int r = 0; r < 4; ++r) {
                    int m = 16 * mi + 4 * l4 + r;
                    sm_vt[m * DP + cu] = f2b(acc[mi][ni][r] + b2v);
                }
            }
        }
    }
    __syncthreads();

    // ---- Phase 7: residual add (regs) + scatter ----
    {
        float* op = out + (size_t)b * DCH * plane + pix;
        #pragma unroll
        for (int i = 0; i < CPT; i += 2) {
            unsigned int pk = xres[i / 2];
            float o0 = b2f(sm_vt[t * DP + d0 + i])     + b2f((unsigned short)(pk & 0xFFFF));
            float o1 = b2f(sm_vt[t * DP + d0 + i + 1]) + b2f((unsigned short)(pk >> 16));
            op[(size_t)(d0 + i) * plane]     = o0;
            op[(size_t)(d0 + i + 1) * plane] = o1;
        }
    }
}

// ---------------- single fused kernel: all 3 segment classes in one grid ----------------
__global__ __launch_bounds__(512, 4)
void gmlp_all(const float* __restrict__ x,
              const float* __restrict__ ln1_g, const float* __restrict__ ln1_b,
              const float* __restrict__ b1,
              const float* __restrict__ sgu_g, const float* __restrict__ sgu_b,
              const float* __restrict__ bsf, const float* __restrict__ bsh,
              const float* __restrict__ bsq, const float* __restrict__ b2,
              const unsigned short* __restrict__ w1t, const unsigned short* __restrict__ w2t,
              const unsigned short* __restrict__ wsf, const unsigned short* __restrict__ wsh,
              const unsigned short* __restrict__ wsq,
              float* __restrict__ out)
{
    __shared__ __align__(16) unsigned char smem[70656];
    const int bid = blockIdx.x;
    const int tid = threadIdx.x;

    if (bid < 3600) {                          // full 8x8 windows
        const int t = tid & 63;
        int b = bid / 225, rem = bid % 225;
        int hr0 = (rem / 15) * 8, wr0 = (rem % 15) * 8;
        gmlp_body<64, 0>(b, hr0, wr0, t >> 3, t & 7,
                         x, ln1_g, ln1_b, b1, sgu_g, sgu_b, bsf, b2, w1t, w2t, wsf, out, smem);
    } else if (bid < 4560) {                   // half strips
        int ix = bid - 3600;
        const int t = tid & 31;
        int b, hr0, wr0, pr, pc;
        if (ix < 480) {                        // l / r vertical strips (8 rows x 4 cols)
            int side = ix / 240, j = ix % 240;
            b = j / 15; hr0 = (j % 15) * 8; wr0 = 120 + 4 * side;
            pr = t >> 2; pc = t & 3;
        } else {                               // u / d horizontal strips (4 rows x 8 cols)
            ix -= 480; int side = ix / 240, j = ix % 240;
            b = j / 15; hr0 = 120 + 4 * side; wr0 = (j % 15) * 8;
            pr = t >> 3; pc = t & 7;
        }
        gmlp_body<32, 1>(b, hr0, wr0, pr, pc,
                         x, ln1_g, ln1_b, b1, sgu_g, sgu_b, bsh, b2, w1t, w2t, wsh, out, smem);
    } else {                                   // quadrants 4x4
        int ix = bid - 4560;
        const int t = tid & 15;
        int quad = ix >> 4, b = ix & 15;
        int hr0 = 120 + 4 * (quad >> 1), wr0 = 120 + 4 * (quad & 1);
        gmlp_body<16, 2>(b, hr0, wr0, t >> 2, t & 3,
                         x, ln1_g, ln1_b, b1, sgu_g, sgu_b, bsq, b2, w1t, w2t, wsq, out, smem);
    }
}

extern "C" void kernel_launch(void* const* d_in, const int* in_sizes, int n_in,
                              void* d_out, int out_size, void* d_ws, size_t ws_size,
                              hipStream_t stream)
{
    (void)in_sizes; (void)n_in; (void)out_size; (void)ws_size;
    const float* x     = (const float*)d_in[0];
    const float* ln1_g = (const float*)d_in[1];
    const float* ln1_b = (const float*)d_in[2];
    const float* W1    = (const float*)d_in[3];
    const float* b1    = (const float*)d_in[4];
    const float* sgu_g = (const float*)d_in[5];
    const float* sgu_b = (const float*)d_in[6];
    const float* Wsf   = (const float*)d_in[7];
    const float* bsf   = (const float*)d_in[8];
    const float* Wsh   = (const float*)d_in[9];
    const float* bsh   = (const float*)d_in[10];
    const float* Wsq   = (const float*)d_in[11];
    const float* bsq   = (const float*)d_in[12];
    const float* W2    = (const float*)d_in[13];
    const float* b2    = (const float*)d_in[14];
    float* out = (float*)d_out;

    unsigned short* w1t = (unsigned short*)d_ws;       // 3*512*256 bf16
    unsigned short* w2t = w1t + 3 * 512 * 256;         // 3*256*256 bf16
    unsigned short* wsf = w2t + 3 * 256 * 256;         // 64*64
    unsigned short* wsh = wsf + 64 * 64;               // 32*32
    unsigned short* wsq = wsh + 32 * 32;               // 16*16

    hipLaunchKernelGGL(prep_weights, dim3(1536), dim3(256), 0, stream,
                       W1, W2, Wsf, Wsh, Wsq, w1t, w2t, wsf, wsh, wsq);

    hipLaunchKernelGGL(gmlp_all, dim3(4624), dim3(512), 0, stream,
                       x, ln1_g, ln1_b, b1, sgu_g, sgu_b,
                       bsf, bsh, bsq, b2, w1t, w2t, wsf, wsh, wsq, out);
}